// Round 5
// baseline (375.215 us; speedup 1.0000x reference)
//
#include <hip/hip_runtime.h>
#include <hip/hip_bf16.h>

// ---------------------------------------------------------------------------
// GAT forward: 3 layers, N=100k nodes, D=64, E=1.6M edges (+N self loops).
// CSR via 2-phase bucket partition. Per layer:
//   gemm_k: h = x @ [W | W.a_s | W.a_d] on MFMA f32_16x16x32_f16; B frags
//           pre-swizzled to fragment layout (conv_params_k), scores come out
//           of the 5th (augmented) col-tile -> epilogue is stores only.
//   agg_k : register-cached edge softmax + 16-edges-in-flight fp16 gather;
//           writes only x_l (fp16). Mean over layers done once in finalize_k
//           from x0..x3 (no f32 outacc traffic in the hot loop).
// ---------------------------------------------------------------------------

#define BSHIFT 9
#define NPB 512            // nodes per bucket
#define COL_CAP 10240      // LDS col image capacity per bucket (mean ~8700)
#define FRAG_STRIDE 5120   // 10 frags * 64 lanes * 8 halves per layer

typedef _Float16 v8h __attribute__((ext_vector_type(8)));
typedef float v4f __attribute__((ext_vector_type(4)));
typedef unsigned short u16x8 __attribute__((ext_vector_type(8)));

__device__ inline float bf2f(unsigned short u) {
    return __uint_as_float(((unsigned int)u) << 16);
}
__device__ inline unsigned short f2bf(float v) {
    __hip_bfloat16 b = __float2bfloat16(v);
    return *reinterpret_cast<unsigned short*>(&b);
}
__device__ inline unsigned short f2h_u(float v) {
    return __builtin_bit_cast(unsigned short, (_Float16)v);
}
__device__ inline float h2f_u(unsigned short u) {
    return (float)__builtin_bit_cast(_Float16, u);
}

// also zeros the bucket histogram
__global__ __launch_bounds__(256) void detect_bf16_k(const unsigned int* raw, int* flag, int* ghist) {
    __shared__ int sc;
    if (threadIdx.x == 0) sc = 0;
    ghist[threadIdx.x] = 0;
    __syncthreads();
    int c = 0;
    for (int i = threadIdx.x; i < 4096; i += 256) {
        unsigned int b = (raw[i] >> 8) & 0x7Fu;   // bits 15:8, sign masked
        if (b >= 0x3Bu && b <= 0x3Fu) c++;        // bf16 exponent byte range
    }
    atomicAdd(&sc, c);
    __syncthreads();
    if (threadIdx.x == 0) *flag = (sc > 2048) ? 1 : 0;
}

__device__ inline float load_in(const void* p, int i, int isbf) {
    if (isbf) return bf2f(((const unsigned short*)p)[i]);
    return ((const float*)p)[i];
}

// emb -> x0 (fp16)
__global__ __launch_bounds__(256) void conv_emb_k(const void* emb, unsigned short* x0,
                                                  int n, const int* flag) {
    int i = blockIdx.x * 256 + threadIdx.x;
    if (i >= n) return;
    x0[i] = f2h_u(load_in(emb, i, *flag));
}

// W -> MFMA fragment layout; score tile (frags 8,9) holds W.a_s (col 0) and
// W.a_d (col 1), zeros elsewhere; bias -> f32.
// Frag layout: B[k][col], col=lane&15, k=(lane>>4)*8+j; frag f=tile*2+kf.
__global__ __launch_bounds__(256) void conv_params_k(const void* W, const void* as_, const void* ad_,
                                                     const void* b_, unsigned short* Whf, float* bf,
                                                     int L_, const int* flag) {
    int i = blockIdx.x * 256 + threadIdx.x;
    int isbf = *flag;
    if (i < L_ * 4096) {
        int l = i >> 12, rem = i & 4095;
        int k = rem >> 6, c64 = rem & 63;
        int t = c64 >> 4, c = c64 & 15;
        int kf = k >> 5, quad = (k >> 3) & 3, j = k & 7;
        int f = t * 2 + kf, lane = quad * 16 + c;
        Whf[l * FRAG_STRIDE + (f * 64 + lane) * 8 + j] = f2h_u(load_in(W, i, isbf));
    }
    if (i < L_ * 1024) {                 // score tile: frags 8 (k<32), 9 (k>=32)
        int l = i >> 10, r = i & 1023;
        int kf = r >> 9, rr = r & 511;
        int lane = rr >> 3, j = rr & 7;
        int c = lane & 15, quad = lane >> 4;
        int k = kf * 32 + quad * 8 + j;
        float val = 0.f;
        if (c < 2) {
            const void* av = c ? ad_ : as_;
            float dot = 0.f;
            for (int cc = 0; cc < 64; ++cc)
                dot += load_in(W, l * 4096 + k * 64 + cc, isbf) * load_in(av, l * 64 + cc, isbf);
            val = dot;                   // (W @ a)[k]
        }
        Whf[l * FRAG_STRIDE + ((8 + kf) * 64 + lane) * 8 + j] = f2h_u(val);
    }
    if (i < L_ * 64) bf[i] = load_in(b_, i, isbf);
}

// ---- CSR build: bucket partition ------------------------------------------

__global__ __launch_bounds__(256) void hist_k(const int* dst, int* ghist, int E) {
    __shared__ int h[256];
    h[threadIdx.x] = 0;
    __syncthreads();
    int cs = blockIdx.x * 4096;
    int ce = min(cs + 4096, E);
    for (int i = cs + threadIdx.x; i < ce; i += 256)
        atomicAdd(&h[dst[i] >> BSHIFT], 1);
    __syncthreads();
    if (h[threadIdx.x]) atomicAdd(&ghist[threadIdx.x], h[threadIdx.x]);
}

__global__ __launch_bounds__(256) void scan_nb_k(const int* ghist, int* pairs_base, int* col_base,
                                                 int* cursor, int* rowptr, int N, int E, int NB) {
    __shared__ int s1[256], s2[256];
    int t = threadIdx.x;
    int hv = (t < NB) ? ghist[t] : 0;
    int npb = (t < NB) ? min(N - (t << BSHIFT), NPB) : 0;
    s1[t] = hv; s2[t] = hv + npb;
    __syncthreads();
    for (int off = 1; off < 256; off <<= 1) {
        int t1 = (t >= off) ? s1[t - off] : 0;
        int t2 = (t >= off) ? s2[t - off] : 0;
        __syncthreads();
        s1[t] += t1; s2[t] += t2;
        __syncthreads();
    }
    if (t < NB) {
        pairs_base[t] = s1[t] - hv;
        cursor[t]     = s1[t] - hv;
        col_base[t]   = s2[t] - (hv + npb);
    }
    if (t == 0) rowptr[N] = E + N;
}

__global__ __launch_bounds__(256) void partition_k(const int* __restrict__ src,
                                                   const int* __restrict__ dst,
                                                   int* cursor, uint2* __restrict__ pairs,
                                                   int E, int NB) {
    __shared__ int cnt[256], base[256], rk[256];
    int t = threadIdx.x;
    cnt[t] = 0; rk[t] = 0;
    __syncthreads();
    int cs = blockIdx.x * 4096;
    int ce = min(cs + 4096, E);
    for (int i = cs + t; i < ce; i += 256)
        atomicAdd(&cnt[dst[i] >> BSHIFT], 1);
    __syncthreads();
    if (t < NB && cnt[t]) base[t] = atomicAdd(&cursor[t], cnt[t]);
    __syncthreads();
    for (int i = cs + t; i < ce; i += 256) {
        int d = dst[i];
        int b = d >> BSHIFT;
        int r = atomicAdd(&rk[b], 1);
        pairs[base[b] + r] = make_uint2((unsigned)src[i], (unsigned)d);
    }
}

__global__ __launch_bounds__(512) void build_k(const uint2* __restrict__ pairs,
                                               const int* __restrict__ ghist,
                                               const int* __restrict__ pairs_base,
                                               const int* __restrict__ col_base,
                                               int* __restrict__ rowptr, int* __restrict__ col,
                                               int N) {
    __shared__ int cnt[512], cnt2[512], sc[512], off[513];
    __shared__ int col_lds[COL_CAP];
    int b = blockIdx.x, t = threadIdx.x;
    int nloc = min(N - (b << BSHIFT), NPB);
    int ne = ghist[b], pb = pairs_base[b], cb = col_base[b];
    cnt[t] = 0; cnt2[t] = 0;
    __syncthreads();
    for (int i = t; i < ne; i += 512)
        atomicAdd(&cnt[pairs[pb + i].y & (NPB - 1)], 1);
    __syncthreads();
    int v = cnt[t] + (t < nloc ? 1 : 0);    // +1 self loop
    sc[t] = v;
    __syncthreads();
    for (int o = 1; o < 512; o <<= 1) {
        int tv = (t >= o) ? sc[t - o] : 0;
        __syncthreads();
        sc[t] += tv;
        __syncthreads();
    }
    off[t + 1] = sc[t];
    if (t == 0) off[0] = 0;
    __syncthreads();
    if (t < nloc) rowptr[(b << BSHIFT) + t] = cb + off[t];
    int total = off[nloc];                   // == ne + nloc
    bool fit = (total <= COL_CAP);
    for (int i = t; i < ne; i += 512) {
        uint2 p = pairs[pb + i];
        int loc = p.y & (NPB - 1);
        int pos = off[loc] + atomicAdd(&cnt2[loc], 1);
        if (fit) col_lds[pos] = (int)p.x;
        else     col[cb + pos] = (int)p.x;   // overflow fallback
    }
    if (t < nloc) {
        int pos = off[t + 1] - 1;            // self-loop slot
        int sv = (b << BSHIFT) + t;
        if (fit) col_lds[pos] = sv;
        else     col[cb + pos] = sv;
    }
    __syncthreads();
    if (fit)
        for (int i = t; i < total; i += 512) col[cb + i] = col_lds[i];
}

// ---- per-layer compute -----------------------------------------------------

// MFMA GEMM, 16-node strip per wave, 5 col-tiles (4 = h, 1 = scores).
// A: row=lane&15, k=(lane>>4)*8+j.  C: col=lane&15, row=(lane>>4)*4+reg.
__global__ __launch_bounds__(256) void gemm_k(const unsigned short* __restrict__ x,
                                              const unsigned short* __restrict__ Whf,
                                              unsigned short* __restrict__ h,
                                              float* __restrict__ es, float* __restrict__ ed,
                                              int n, int nblk, int nwaves) {
    int lane = threadIdx.x & 63;
    int gwave = (blockIdx.x * 256 + threadIdx.x) >> 6;
    int c = lane & 15, quad = lane >> 4;

    v8h bfr[10];
    #pragma unroll
    for (int f = 0; f < 10; ++f)
        bfr[f] = *(const v8h*)(Whf + (size_t)(f * 64 + lane) * 8);

    v4f z = {0.f, 0.f, 0.f, 0.f};
    for (int nb = gwave; nb < nblk; nb += nwaves) {
        int base = nb * 16;
        int m = base + c; if (m >= n) m = n - 1;
        const v8h a0 = *(const v8h*)(x + (size_t)m * 64 + quad * 8);
        const v8h a1 = *(const v8h*)(x + (size_t)m * 64 + 32 + quad * 8);
        v4f acc[5];
        #pragma unroll
        for (int t = 0; t < 5; ++t) {
            acc[t] = __builtin_amdgcn_mfma_f32_16x16x32_f16(a0, bfr[2 * t], z, 0, 0, 0);
            acc[t] = __builtin_amdgcn_mfma_f32_16x16x32_f16(a1, bfr[2 * t + 1], acc[t], 0, 0, 0);
        }
        #pragma unroll
        for (int r = 0; r < 4; ++r) {
            int row = base + quad * 4 + r;
            if (row < n) {
                #pragma unroll
                for (int t = 0; t < 4; ++t)
                    h[(size_t)row * 64 + t * 16 + c] = f2h_u(acc[t][r]);
                if (c == 0) es[row] = acc[4][r];
                if (c == 1) ed[row] = acc[4][r];
            }
        }
    }
}

__device__ inline float elu_f(float v) { return v > 0.f ? v : (__expf(v) - 1.f); }

// One wave per dst node. Fast path (deg<=64): edge list cached in registers,
// one gather pass for scores, then 16 edges in flight (2 groups of 8 x 16B).
__global__ __launch_bounds__(256) void agg_k(const unsigned short* __restrict__ h,
                                             const float* __restrict__ es,
                                             const float* __restrict__ ed, const int* __restrict__ rowptr,
                                             const int* __restrict__ col, const float* __restrict__ bias,
                                             unsigned short* __restrict__ xo, int n) {
    int gw = (blockIdx.x * 256 + threadIdx.x) >> 6;
    int lane = threadIdx.x & 63;
    if (gw >= n) return;
    int start = rowptr[gw], end = rowptr[gw + 1];
    int deg = end - start;
    float edd = ed[gw];

    if (deg <= 64) {
        int c = 0;
        float e = -1e30f;
        if (lane < deg) {
            c = col[start + lane];
            float t = es[c] + edd;
            e = t > 0.f ? t : 0.2f * t;
        }
        float m = e;
        #pragma unroll
        for (int off = 32; off; off >>= 1) m = fmaxf(m, __shfl_xor(m, off));
        float ex = (lane < deg) ? __expf(e - m) : 0.f;
        float sum = ex;
        #pragma unroll
        for (int off = 32; off; off >>= 1) sum += __shfl_xor(sum, off);
        float a = ex / (sum + 1e-16f);     // per-edge alpha, lane = edge slot

        int g = lane >> 3, j = lane & 7;   // 8 edge groups x 8 lanes x 16B
        float acc[8];
        #pragma unroll
        for (int i = 0; i < 8; ++i) acc[i] = 0.f;
        for (int t = 0; t < deg; t += 16) {
            int i0 = t + g, i1 = t + 8 + g;
            int   s0  = __shfl(c, i0), s1 = __shfl(c, i1);
            float al0 = __shfl(a, i0), al1 = __shfl(a, i1);
            bool p0 = i0 < deg, p1 = i1 < deg;
            u16x8 hv0, hv1;
            if (p0) hv0 = *(const u16x8*)(h + (size_t)s0 * 64 + j * 8);
            if (p1) hv1 = *(const u16x8*)(h + (size_t)s1 * 64 + j * 8);
            if (p0) {
                #pragma unroll
                for (int i = 0; i < 8; ++i) acc[i] = fmaf(al0, h2f_u(hv0[i]), acc[i]);
            }
            if (p1) {
                #pragma unroll
                for (int i = 0; i < 8; ++i) acc[i] = fmaf(al1, h2f_u(hv1[i]), acc[i]);
            }
        }
        #pragma unroll
        for (int off = 8; off < 64; off <<= 1)
            #pragma unroll
            for (int i = 0; i < 8; ++i)
                acc[i] += __shfl_xor(acc[i], off);

        if (g == 0) {
            u16x8 o;
            #pragma unroll
            for (int i = 0; i < 8; ++i)
                o[i] = f2h_u(elu_f(acc[i] + bias[j * 8 + i]));
            *(u16x8*)(xo + (size_t)gw * 64 + j * 8) = o;
        }
    } else {
        // rare slow path: 3-pass scalar
        float m = -1e30f;
        for (int k = start + lane; k < end; k += 64) {
            float e = es[col[k]] + edd;
            e = e > 0.f ? e : 0.2f * e;
            m = fmaxf(m, e);
        }
        #pragma unroll
        for (int off = 32; off; off >>= 1) m = fmaxf(m, __shfl_xor(m, off));
        float sum = 0.f;
        for (int k = start + lane; k < end; k += 64) {
            float e = es[col[k]] + edd;
            e = e > 0.f ? e : 0.2f * e;
            sum += __expf(e - m);
        }
        #pragma unroll
        for (int off = 32; off; off >>= 1) sum += __shfl_xor(sum, off);
        float inv = 1.f / (sum + 1e-16f);
        float acc = 0.f;
        for (int k = start; k < end; ++k) {
            int s = col[k];
            float e = es[s] + edd;
            e = e > 0.f ? e : 0.2f * e;
            float al = __expf(e - m) * inv;
            acc = fmaf(al, h2f_u(h[(size_t)s * 64 + lane]), acc);
        }
        xo[(size_t)gw * 64 + lane] = f2h_u(elu_f(acc + bias[lane]));
    }
}

// mean over {x0..x3}, 8 elems/thread
__global__ __launch_bounds__(256) void finalize_k(const unsigned short* __restrict__ x0,
                                                  const unsigned short* __restrict__ x1,
                                                  const unsigned short* __restrict__ x2,
                                                  const unsigned short* __restrict__ x3,
                                                  void* __restrict__ out, const int* flag, int n8) {
    int i = blockIdx.x * 256 + threadIdx.x;
    if (i >= n8) return;
    size_t base = (size_t)i * 8;
    u16x8 a = *(const u16x8*)(x0 + base);
    u16x8 b = *(const u16x8*)(x1 + base);
    u16x8 c = *(const u16x8*)(x2 + base);
    u16x8 d = *(const u16x8*)(x3 + base);
    float v[8];
    #pragma unroll
    for (int k = 0; k < 8; ++k)
        v[k] = (h2f_u(a[k]) + h2f_u(b[k]) + h2f_u(c[k]) + h2f_u(d[k])) * 0.25f;
    if (*flag) {
        u16x8 o;
        #pragma unroll
        for (int k = 0; k < 8; ++k) o[k] = f2bf(v[k]);
        *(u16x8*)((unsigned short*)out + base) = o;
    } else {
        float4 o0 = make_float4(v[0], v[1], v[2], v[3]);
        float4 o1 = make_float4(v[4], v[5], v[6], v[7]);
        *(float4*)((float*)out + base) = o0;
        *(float4*)((float*)out + base + 4) = o1;
    }
}

// ---------------------------------------------------------------------------

extern "C" void kernel_launch(void* const* d_in, const int* in_sizes, int n_in,
                              void* d_out, int out_size, void* d_ws, size_t ws_size,
                              hipStream_t stream) {
    const int*  edge = (const int*)d_in[0];
    const void* emb  = d_in[1];
    const void* W    = d_in[2];
    const void* as_  = d_in[3];
    const void* ad_  = d_in[4];
    const void* b_   = d_in[5];

    const int E = in_sizes[0] / 2;
    const int N = in_sizes[1] / 64;
    const int L = in_sizes[2] / 4096;
    const int NB = (N + NPB - 1) >> BSHIFT;     // 196 buckets (<=256)
    const size_t N64 = (size_t)N * 64;

    char* p = (char*)d_ws;
    auto take = [&](size_t bytes) { char* r = p; p += (bytes + 255) & ~(size_t)255; return r; };
    unsigned short* x0 = (unsigned short*)take(N64 * 2);
    unsigned short* x1 = (unsigned short*)take(N64 * 2);
    unsigned short* x3 = (unsigned short*)take(N64 * 2);
    unsigned short* h  = (unsigned short*)take(N64 * 2);
    uint2* pairs   = (uint2*)take((size_t)E * 8 > N64 * 2 ? (size_t)E * 8 : N64 * 2);
    unsigned short* x2 = (unsigned short*)pairs;   // pairs dead after build_k
    float* es      = (float*)take((size_t)N * 4);
    float* ed      = (float*)take((size_t)N * 4);
    unsigned short* Whf = (unsigned short*)take((size_t)L * FRAG_STRIDE * 2);
    float* bf      = (float*)take((size_t)L * 64 * 4);
    int* rowptr    = (int*)take((size_t)(N + 1) * 4);
    int* col       = (int*)take((size_t)(E + N) * 4);
    int* ghist     = (int*)take(256 * 4);
    int* pairs_base= (int*)take(256 * 4);
    int* col_base  = (int*)take(256 * 4);
    int* cursor    = (int*)take(256 * 4);
    int* flag      = (int*)take(4);

    const int* srcp = edge;
    const int* dstp = edge + E;
    int nchunk = (E + 4095) / 4096;

    detect_bf16_k<<<1, 256, 0, stream>>>((const unsigned int*)emb, flag, ghist);
    conv_emb_k<<<(int)((N64 + 255) / 256), 256, 0, stream>>>(emb, x0, (int)N64, flag);
    conv_params_k<<<(L * 4096 + 255) / 256, 256, 0, stream>>>(W, as_, ad_, b_, Whf, bf, L, flag);

    hist_k<<<nchunk, 256, 0, stream>>>(dstp, ghist, E);
    scan_nb_k<<<1, 256, 0, stream>>>(ghist, pairs_base, col_base, cursor, rowptr, N, E, NB);
    partition_k<<<nchunk, 256, 0, stream>>>(srcp, dstp, cursor, pairs, E, NB);
    build_k<<<NB, 512, 0, stream>>>(pairs, ghist, pairs_base, col_base, rowptr, col, N);

    const int nblk = (N + 15) / 16;
    const int ggrid = 512;                      // 2048 waves, ~3 strips each
    unsigned short* xs[4] = {x0, x1, x2, x3};
    for (int l = 0; l < L; ++l) {
        gemm_k<<<ggrid, 256, 0, stream>>>(xs[l], Whf + (size_t)l * FRAG_STRIDE,
                                          h, es, ed, N, nblk, ggrid * 4);
        agg_k<<<(N + 3) / 4, 256, 0, stream>>>(h, es, ed, rowptr, col, bf + l * 64, xs[l + 1], N);
    }
    finalize_k<<<(int)((N64 / 8 + 255) / 256), 256, 0, stream>>>(x0, x1, x2, x3, d_out, flag,
                                                                 (int)(N64 / 8));
}

// Round 6
// 353.787 us; speedup vs baseline: 1.0606x; 1.0606x over previous
//
#include <hip/hip_runtime.h>
#include <hip/hip_bf16.h>

// ---------------------------------------------------------------------------
// GAT forward: 3 layers, N=100k nodes, D=64, E=1.6M edges (+N self loops).
// CSR build is fully atomic-free at global scope:
//   hist_k   : per-chunk bucket histograms -> bh[bucket][chunk] (plain stores)
//   scanb_k  : per-bucket exclusive scan over chunks (block per bucket)
//   scan_nb_k: cross-bucket scan -> pairs_base/col_base
//   partition_k: one pass, base = pairs_base+bh prefix, LDS rank only
//   build_k  : per-bucket LDS counting sort -> rowptr/col
// Per layer: gemm_k (MFMA f16, pre-swizzled B frags, scores via augmented
// 5th col-tile), agg_k (register-cached softmax + 16-edge-in-flight gather).
// Last agg fuses the 4-layer mean and writes d_out directly.
// ---------------------------------------------------------------------------

#define BSHIFT 9
#define NPB 512            // nodes per bucket
#define COL_CAP 10240      // LDS col image capacity per bucket (mean ~8700)
#define FRAG_STRIDE 5120   // 10 frags * 64 lanes * 8 halves per layer
#define CHUNK 4096         // edges per partition chunk

typedef _Float16 v8h __attribute__((ext_vector_type(8)));
typedef float v4f __attribute__((ext_vector_type(4)));
typedef unsigned short u16x8 __attribute__((ext_vector_type(8)));

__device__ inline float bf2f(unsigned short u) {
    return __uint_as_float(((unsigned int)u) << 16);
}
__device__ inline unsigned short f2bf(float v) {
    __hip_bfloat16 b = __float2bfloat16(v);
    return *reinterpret_cast<unsigned short*>(&b);
}
__device__ inline unsigned short f2h_u(float v) {
    return __builtin_bit_cast(unsigned short, (_Float16)v);
}
__device__ inline float h2f_u(unsigned short u) {
    return (float)__builtin_bit_cast(_Float16, u);
}

__global__ __launch_bounds__(256) void detect_bf16_k(const unsigned int* raw, int* flag) {
    __shared__ int sc;
    if (threadIdx.x == 0) sc = 0;
    __syncthreads();
    int c = 0;
    for (int i = threadIdx.x; i < 4096; i += 256) {
        unsigned int b = (raw[i] >> 8) & 0x7Fu;   // bits 15:8, sign masked
        if (b >= 0x3Bu && b <= 0x3Fu) c++;        // bf16 exponent byte range
    }
    atomicAdd(&sc, c);
    __syncthreads();
    if (threadIdx.x == 0) *flag = (sc > 2048) ? 1 : 0;
}

__device__ inline float load_in(const void* p, int i, int isbf) {
    if (isbf) return bf2f(((const unsigned short*)p)[i]);
    return ((const float*)p)[i];
}

// fused conversions: emb -> x0 fp16; W -> MFMA frag layout with augmented
// score tile (frags 8,9: col0 = W.a_s, col1 = W.a_d); bias -> f32.
__global__ __launch_bounds__(256) void conv_k(const void* emb, const void* W, const void* as_,
                                              const void* ad_, const void* b_, unsigned short* x0,
                                              unsigned short* Whf, float* bf, int n, int L_,
                                              const int* flag) {
    int i = blockIdx.x * 256 + threadIdx.x;
    int isbf = *flag;
    if (i < n) x0[i] = f2h_u(load_in(emb, i, isbf));
    if (i < L_ * 4096) {
        int l = i >> 12, rem = i & 4095;
        int k = rem >> 6, c64 = rem & 63;
        int t = c64 >> 4, c = c64 & 15;
        int kf = k >> 5, quad = (k >> 3) & 3, j = k & 7;
        int f = t * 2 + kf, lane = quad * 16 + c;
        Whf[l * FRAG_STRIDE + (f * 64 + lane) * 8 + j] = f2h_u(load_in(W, i, isbf));
    }
    if (i < L_ * 1024) {                 // score tile: frags 8 (k<32), 9 (k>=32)
        int l = i >> 10, r = i & 1023;
        int kf = r >> 9, rr = r & 511;
        int lane = rr >> 3, j = rr & 7;
        int c = lane & 15, quad = lane >> 4;
        int k = kf * 32 + quad * 8 + j;
        float val = 0.f;
        if (c < 2) {
            const void* av = c ? ad_ : as_;
            float dot = 0.f;
            for (int cc = 0; cc < 64; ++cc)
                dot += load_in(W, l * 4096 + k * 64 + cc, isbf) * load_in(av, l * 64 + cc, isbf);
            val = dot;                   // (W @ a)[k]
        }
        Whf[l * FRAG_STRIDE + ((8 + kf) * 64 + lane) * 8 + j] = f2h_u(val);
    }
    if (i < L_ * 64) bf[i] = load_in(b_, i, isbf);
}

// ---- CSR build: atomic-free bucket partition -------------------------------

// per-chunk bucket histogram -> bh[bucket*nchunk + chunk]; no global atomics
__global__ __launch_bounds__(256) void hist_k(const int* __restrict__ dst, int* __restrict__ bh,
                                              int E, int nchunk) {
    __shared__ int h[256];
    h[threadIdx.x] = 0;
    __syncthreads();
    int cs = blockIdx.x * CHUNK;
    int ce = min(cs + CHUNK, E);
    for (int i = cs + threadIdx.x; i < ce; i += 256)
        atomicAdd(&h[dst[i] >> BSHIFT], 1);
    __syncthreads();
    bh[threadIdx.x * nchunk + blockIdx.x] = h[threadIdx.x];
}

// block per bucket: exclusive scan of the chunk row (nchunk <= 512), total->ghist
__global__ __launch_bounds__(256) void scanb_k(int* __restrict__ bh, int* __restrict__ ghist,
                                               int nchunk) {
    __shared__ int s[256];
    int b = blockIdx.x, t = threadIdx.x;
    int i0 = 2 * t, i1 = 2 * t + 1;
    int v0 = (i0 < nchunk) ? bh[b * nchunk + i0] : 0;
    int v1 = (i1 < nchunk) ? bh[b * nchunk + i1] : 0;
    int p = v0 + v1;
    s[t] = p;
    __syncthreads();
    for (int off = 1; off < 256; off <<= 1) {
        int tv = (t >= off) ? s[t - off] : 0;
        __syncthreads();
        s[t] += tv;
        __syncthreads();
    }
    int excl = s[t] - p;
    if (i0 < nchunk) bh[b * nchunk + i0] = excl;
    if (i1 < nchunk) bh[b * nchunk + i1] = excl + v0;
    if (t == 255) ghist[b] = s[255];
}

// single block: cross-bucket exclusive scans (pairs sizes, col sizes)
__global__ __launch_bounds__(256) void scan_nb_k(const int* ghist, int* pairs_base, int* col_base,
                                                 int* rowptr, int N, int E, int NB) {
    __shared__ int s1[256], s2[256];
    int t = threadIdx.x;
    int hv = (t < NB) ? ghist[t] : 0;
    int npb = (t < NB) ? min(N - (t << BSHIFT), NPB) : 0;
    s1[t] = hv; s2[t] = hv + npb;
    __syncthreads();
    for (int off = 1; off < 256; off <<= 1) {
        int t1 = (t >= off) ? s1[t - off] : 0;
        int t2 = (t >= off) ? s2[t - off] : 0;
        __syncthreads();
        s1[t] += t1; s2[t] += t2;
        __syncthreads();
    }
    if (t < NB) {
        pairs_base[t] = s1[t] - hv;
        col_base[t]   = s2[t] - (hv + npb);
    }
    if (t == 0) rowptr[N] = E + N;
}

// one pass, zero global atomics: base from scanned histograms, rank via LDS
__global__ __launch_bounds__(256) void partition_k(const int* __restrict__ src,
                                                   const int* __restrict__ dst,
                                                   const int* __restrict__ bh,
                                                   const int* __restrict__ pairs_base,
                                                   uint2* __restrict__ pairs,
                                                   int E, int NB, int nchunk) {
    __shared__ int base[256], rk[256];
    int t = threadIdx.x;
    base[t] = (t < NB) ? pairs_base[t] + bh[t * nchunk + blockIdx.x] : 0;
    rk[t] = 0;
    __syncthreads();
    int cs = blockIdx.x * CHUNK;
    int ce = min(cs + CHUNK, E);
    for (int i = cs + t; i < ce; i += 256) {
        int d = dst[i];
        int b = d >> BSHIFT;
        int r = atomicAdd(&rk[b], 1);
        pairs[base[b] + r] = make_uint2((unsigned)src[i], (unsigned)d);
    }
}

__global__ __launch_bounds__(512) void build_k(const uint2* __restrict__ pairs,
                                               const int* __restrict__ ghist,
                                               const int* __restrict__ pairs_base,
                                               const int* __restrict__ col_base,
                                               int* __restrict__ rowptr, int* __restrict__ col,
                                               int N) {
    __shared__ int cnt[512], cnt2[512], sc[512], off[513];
    __shared__ int col_lds[COL_CAP];
    int b = blockIdx.x, t = threadIdx.x;
    int nloc = min(N - (b << BSHIFT), NPB);
    int ne = ghist[b], pb = pairs_base[b], cb = col_base[b];
    cnt[t] = 0; cnt2[t] = 0;
    __syncthreads();
    for (int i = t; i < ne; i += 512)
        atomicAdd(&cnt[pairs[pb + i].y & (NPB - 1)], 1);
    __syncthreads();
    int v = cnt[t] + (t < nloc ? 1 : 0);    // +1 self loop
    sc[t] = v;
    __syncthreads();
    for (int o = 1; o < 512; o <<= 1) {
        int tv = (t >= o) ? sc[t - o] : 0;
        __syncthreads();
        sc[t] += tv;
        __syncthreads();
    }
    off[t + 1] = sc[t];
    if (t == 0) off[0] = 0;
    __syncthreads();
    if (t < nloc) rowptr[(b << BSHIFT) + t] = cb + off[t];
    int total = off[nloc];                   // == ne + nloc
    bool fit = (total <= COL_CAP);
    for (int i = t; i < ne; i += 512) {
        uint2 p = pairs[pb + i];
        int loc = p.y & (NPB - 1);
        int pos = off[loc] + atomicAdd(&cnt2[loc], 1);
        if (fit) col_lds[pos] = (int)p.x;
        else     col[cb + pos] = (int)p.x;   // overflow fallback
    }
    if (t < nloc) {
        int pos = off[t + 1] - 1;            // self-loop slot
        int sv = (b << BSHIFT) + t;
        if (fit) col_lds[pos] = sv;
        else     col[cb + pos] = sv;
    }
    __syncthreads();
    if (fit)
        for (int i = t; i < total; i += 512) col[cb + i] = col_lds[i];
}

// ---- per-layer compute -----------------------------------------------------

// MFMA GEMM, 16-node strip per wave, 5 col-tiles (4 = h, 1 = scores).
// A: row=lane&15, k=(lane>>4)*8+j.  C: col=lane&15, row=(lane>>4)*4+reg.
__global__ __launch_bounds__(256) void gemm_k(const unsigned short* __restrict__ x,
                                              const unsigned short* __restrict__ Whf,
                                              unsigned short* __restrict__ h,
                                              float* __restrict__ es, float* __restrict__ ed,
                                              int n, int nblk, int nwaves) {
    int lane = threadIdx.x & 63;
    int gwave = (blockIdx.x * 256 + threadIdx.x) >> 6;
    int c = lane & 15, quad = lane >> 4;

    v8h bfr[10];
    #pragma unroll
    for (int f = 0; f < 10; ++f)
        bfr[f] = *(const v8h*)(Whf + (size_t)(f * 64 + lane) * 8);

    v4f z = {0.f, 0.f, 0.f, 0.f};
    for (int nb = gwave; nb < nblk; nb += nwaves) {
        int base = nb * 16;
        int m = base + c; if (m >= n) m = n - 1;
        const v8h a0 = *(const v8h*)(x + (size_t)m * 64 + quad * 8);
        const v8h a1 = *(const v8h*)(x + (size_t)m * 64 + 32 + quad * 8);
        v4f acc[5];
        #pragma unroll
        for (int t = 0; t < 5; ++t) {
            acc[t] = __builtin_amdgcn_mfma_f32_16x16x32_f16(a0, bfr[2 * t], z, 0, 0, 0);
            acc[t] = __builtin_amdgcn_mfma_f32_16x16x32_f16(a1, bfr[2 * t + 1], acc[t], 0, 0, 0);
        }
        #pragma unroll
        for (int r = 0; r < 4; ++r) {
            int row = base + quad * 4 + r;
            if (row < n) {
                #pragma unroll
                for (int t = 0; t < 4; ++t)
                    h[(size_t)row * 64 + t * 16 + c] = f2h_u(acc[t][r]);
                if (c == 0) es[row] = acc[4][r];
                if (c == 1) ed[row] = acc[4][r];
            }
        }
    }
}

__device__ inline float elu_f(float v) { return v > 0.f ? v : (__expf(v) - 1.f); }

// One wave per dst node. Fast path (deg<=64): edge list cached in registers,
// one gather pass for scores, 16 edges in flight. write_out: fuse 4-layer mean.
__global__ __launch_bounds__(256) void agg_k(const unsigned short* __restrict__ h,
                                             const float* __restrict__ es,
                                             const float* __restrict__ ed, const int* __restrict__ rowptr,
                                             const int* __restrict__ col, const float* __restrict__ bias,
                                             unsigned short* __restrict__ xo,
                                             const unsigned short* __restrict__ x0,
                                             const unsigned short* __restrict__ x1,
                                             const unsigned short* __restrict__ x2,
                                             void* __restrict__ out, const int* __restrict__ flag,
                                             int write_out, int n) {
    int gw = (blockIdx.x * 256 + threadIdx.x) >> 6;
    int lane = threadIdx.x & 63;
    if (gw >= n) return;
    int start = rowptr[gw], end = rowptr[gw + 1];
    int deg = end - start;
    float edd = ed[gw];

    if (deg <= 64) {
        int c = 0;
        float e = -1e30f;
        if (lane < deg) {
            c = col[start + lane];
            float t = es[c] + edd;
            e = t > 0.f ? t : 0.2f * t;
        }
        float m = e;
        #pragma unroll
        for (int off = 32; off; off >>= 1) m = fmaxf(m, __shfl_xor(m, off));
        float ex = (lane < deg) ? __expf(e - m) : 0.f;
        float sum = ex;
        #pragma unroll
        for (int off = 32; off; off >>= 1) sum += __shfl_xor(sum, off);
        float a = ex / (sum + 1e-16f);     // per-edge alpha, lane = edge slot

        int g = lane >> 3, j = lane & 7;   // 8 edge groups x 8 lanes x 16B
        float acc[8];
        #pragma unroll
        for (int i = 0; i < 8; ++i) acc[i] = 0.f;
        for (int t = 0; t < deg; t += 16) {
            int i0 = t + g, i1 = t + 8 + g;
            int   s0  = __shfl(c, i0), s1 = __shfl(c, i1);
            float al0 = __shfl(a, i0), al1 = __shfl(a, i1);
            bool p0 = i0 < deg, p1 = i1 < deg;
            u16x8 hv0, hv1;
            if (p0) hv0 = *(const u16x8*)(h + (size_t)s0 * 64 + j * 8);
            if (p1) hv1 = *(const u16x8*)(h + (size_t)s1 * 64 + j * 8);
            if (p0) {
                #pragma unroll
                for (int i = 0; i < 8; ++i) acc[i] = fmaf(al0, h2f_u(hv0[i]), acc[i]);
            }
            if (p1) {
                #pragma unroll
                for (int i = 0; i < 8; ++i) acc[i] = fmaf(al1, h2f_u(hv1[i]), acc[i]);
            }
        }
        #pragma unroll
        for (int off = 8; off < 64; off <<= 1)
            #pragma unroll
            for (int i = 0; i < 8; ++i)
                acc[i] += __shfl_xor(acc[i], off);

        if (g == 0) {
            size_t base = (size_t)gw * 64 + j * 8;
            float y[8];
            #pragma unroll
            for (int i = 0; i < 8; ++i)
                y[i] = elu_f(acc[i] + bias[j * 8 + i]);
            if (write_out) {
                u16x8 a0v = *(const u16x8*)(x0 + base);
                u16x8 a1v = *(const u16x8*)(x1 + base);
                u16x8 a2v = *(const u16x8*)(x2 + base);
                float v[8];
                #pragma unroll
                for (int i = 0; i < 8; ++i)
                    v[i] = (h2f_u(a0v[i]) + h2f_u(a1v[i]) + h2f_u(a2v[i]) + y[i]) * 0.25f;
                if (*flag) {
                    u16x8 o;
                    #pragma unroll
                    for (int i = 0; i < 8; ++i) o[i] = f2bf(v[i]);
                    *(u16x8*)((unsigned short*)out + base) = o;
                } else {
                    float4 o0 = make_float4(v[0], v[1], v[2], v[3]);
                    float4 o1 = make_float4(v[4], v[5], v[6], v[7]);
                    *(float4*)((float*)out + base) = o0;
                    *(float4*)((float*)out + base + 4) = o1;
                }
            } else {
                u16x8 o;
                #pragma unroll
                for (int i = 0; i < 8; ++i) o[i] = f2h_u(y[i]);
                *(u16x8*)(xo + base) = o;
            }
        }
    } else {
        // rare slow path: 3-pass scalar
        float m = -1e30f;
        for (int k = start + lane; k < end; k += 64) {
            float e = es[col[k]] + edd;
            e = e > 0.f ? e : 0.2f * e;
            m = fmaxf(m, e);
        }
        #pragma unroll
        for (int off = 32; off; off >>= 1) m = fmaxf(m, __shfl_xor(m, off));
        float sum = 0.f;
        for (int k = start + lane; k < end; k += 64) {
            float e = es[col[k]] + edd;
            e = e > 0.f ? e : 0.2f * e;
            sum += __expf(e - m);
        }
        #pragma unroll
        for (int off = 32; off; off >>= 1) sum += __shfl_xor(sum, off);
        float inv = 1.f / (sum + 1e-16f);
        float acc = 0.f;
        for (int k = start; k < end; ++k) {
            int s = col[k];
            float e = es[s] + edd;
            e = e > 0.f ? e : 0.2f * e;
            float al = __expf(e - m) * inv;
            acc = fmaf(al, h2f_u(h[(size_t)s * 64 + lane]), acc);
        }
        size_t base = (size_t)gw * 64 + lane;
        float y = elu_f(acc + bias[lane]);
        if (write_out) {
            float v = (h2f_u(x0[base]) + h2f_u(x1[base]) + h2f_u(x2[base]) + y) * 0.25f;
            if (*flag) ((unsigned short*)out)[base] = f2bf(v);
            else       ((float*)out)[base] = v;
        } else {
            xo[base] = f2h_u(y);
        }
    }
}

// ---------------------------------------------------------------------------

extern "C" void kernel_launch(void* const* d_in, const int* in_sizes, int n_in,
                              void* d_out, int out_size, void* d_ws, size_t ws_size,
                              hipStream_t stream) {
    const int*  edge = (const int*)d_in[0];
    const void* emb  = d_in[1];
    const void* W    = d_in[2];
    const void* as_  = d_in[3];
    const void* ad_  = d_in[4];
    const void* b_   = d_in[5];

    const int E = in_sizes[0] / 2;
    const int N = in_sizes[1] / 64;
    const int L = in_sizes[2] / 4096;
    const int NB = (N + NPB - 1) >> BSHIFT;     // 196 buckets (<=256)
    const int nchunk = (E + CHUNK - 1) / CHUNK; // 391 (<=512)
    const size_t N64 = (size_t)N * 64;

    char* p = (char*)d_ws;
    auto take = [&](size_t bytes) { char* r = p; p += (bytes + 255) & ~(size_t)255; return r; };
    unsigned short* x0 = (unsigned short*)take(N64 * 2);
    unsigned short* x1 = (unsigned short*)take(N64 * 2);
    unsigned short* x3 = (unsigned short*)take(N64 * 2);
    unsigned short* h  = (unsigned short*)take(N64 * 2);
    uint2* pairs   = (uint2*)take((size_t)E * 8 > N64 * 2 ? (size_t)E * 8 : N64 * 2);
    unsigned short* x2 = (unsigned short*)pairs;   // pairs dead after build_k
    float* es      = (float*)take((size_t)N * 4);
    float* ed      = (float*)take((size_t)N * 4);
    unsigned short* Whf = (unsigned short*)take((size_t)L * FRAG_STRIDE * 2);
    float* bf      = (float*)take((size_t)L * 64 * 4);
    int* rowptr    = (int*)take((size_t)(N + 1) * 4);
    int* col       = (int*)take((size_t)(E + N) * 4);
    int* bh        = (int*)take((size_t)256 * 512 * 4);
    int* ghist     = (int*)take(256 * 4);
    int* pairs_base= (int*)take(256 * 4);
    int* col_base  = (int*)take(256 * 4);
    int* flag      = (int*)take(4);

    const int* srcp = edge;
    const int* dstp = edge + E;

    detect_bf16_k<<<1, 256, 0, stream>>>((const unsigned int*)emb, flag);
    conv_k<<<(int)((N64 + 255) / 256), 256, 0, stream>>>(emb, W, as_, ad_, b_, x0, Whf, bf,
                                                         (int)N64, L, flag);

    hist_k<<<nchunk, 256, 0, stream>>>(dstp, bh, E, nchunk);
    scanb_k<<<NB, 256, 0, stream>>>(bh, ghist, nchunk);
    scan_nb_k<<<1, 256, 0, stream>>>(ghist, pairs_base, col_base, rowptr, N, E, NB);
    partition_k<<<nchunk, 256, 0, stream>>>(srcp, dstp, bh, pairs_base, pairs, E, NB, nchunk);
    build_k<<<NB, 512, 0, stream>>>(pairs, ghist, pairs_base, col_base, rowptr, col, N);

    const int nblk = (N + 15) / 16;
    const int ggrid = 512;                      // 2048 waves, ~3 strips each
    unsigned short* xs[4] = {x0, x1, x2, x3};
    for (int l = 0; l < L; ++l) {
        gemm_k<<<ggrid, 256, 0, stream>>>(xs[l], Whf + (size_t)l * FRAG_STRIDE,
                                          h, es, ed, N, nblk, ggrid * 4);
        agg_k<<<(N + 3) / 4, 256, 0, stream>>>(h, es, ed, rowptr, col, bf + l * 64, xs[l + 1],
                                               x0, x1, x2, d_out, flag,
                                               (l == L - 1) ? 1 : 0, N);
    }
}

// Round 8
// 345.951 us; speedup vs baseline: 1.0846x; 1.0226x over previous
//
#include <hip/hip_runtime.h>
#include <hip/hip_bf16.h>

// ---------------------------------------------------------------------------
// GAT forward: 3 layers, N=100k nodes, D=64, E=1.6M edges (+N self loops).
// CSR build atomic-free at global scope, pairs packed to u32 (src|local<<23):
//   conv_hist_k : input conversions (+ per-block dtype detect) + per-chunk
//                 bucket histograms
//   scanb_k -> scan_nb_k -> partition_k -> build_k
// Per layer: gemm_k (MFMA f16, pre-swizzled B frags, scores via augmented
// 5th col-tile), agg_k (2 dst nodes/wave, no-max softmax — mathematically
// identical, 16-rows-in-flight fp16 gather). Last agg fuses 4-layer mean.
// R7 fix: agg grid was half-sized in R6 (6251 blocks vs the 12500 needed).
// ---------------------------------------------------------------------------

#define BSHIFT 9
#define NPB 512            // nodes per bucket
#define COL_CAP 10240      // LDS col image capacity per bucket (mean ~8700)
#define FRAG_STRIDE 5120   // 10 frags * 64 lanes * 8 halves per layer
#define CHUNK 8192         // edges per partition chunk

typedef _Float16 v8h __attribute__((ext_vector_type(8)));
typedef float v4f __attribute__((ext_vector_type(4)));
typedef unsigned short u16x8 __attribute__((ext_vector_type(8)));

__device__ inline float bf2f(unsigned short u) {
    return __uint_as_float(((unsigned int)u) << 16);
}
__device__ inline unsigned short f2bf(float v) {
    __hip_bfloat16 b = __float2bfloat16(v);
    return *reinterpret_cast<unsigned short*>(&b);
}
__device__ inline unsigned short f2h_u(float v) {
    return __builtin_bit_cast(unsigned short, (_Float16)v);
}
__device__ inline float h2f_u(unsigned short u) {
    return (float)__builtin_bit_cast(_Float16, u);
}

__device__ inline float load_in(const void* p, int i, int isbf) {
    if (isbf) return bf2f(((const unsigned short*)p)[i]);
    return ((const float*)p)[i];
}

// per-block dtype detection: all blocks sample the same first 1KB of emb ->
// deterministic identical answer (bf16 ~97% exponent-byte hits, f32 ~4%).
__device__ inline int detect_bf16_blk(const unsigned int* raw) {
    __shared__ int s4[4];
    unsigned int b = (raw[threadIdx.x] >> 8) & 0x7Fu;
    unsigned long long m = __ballot(b >= 0x3Bu && b <= 0x3Fu);
    int wv = threadIdx.x >> 6;
    if ((threadIdx.x & 63) == 0) s4[wv] = __popcll(m);
    __syncthreads();
    return (s4[0] + s4[1] + s4[2] + s4[3]) > 128 ? 1 : 0;
}

// blocks [0, nchunk): per-chunk bucket histogram (no global atomics)
// blocks [nchunk, ...): conversions (emb->x0 fp16, W->frags, bias), flag store
__global__ __launch_bounds__(256) void conv_hist_k(const void* emb, const void* W, const void* as_,
                                                   const void* ad_, const void* b_,
                                                   const int* __restrict__ dst,
                                                   unsigned short* x0, unsigned short* Whf,
                                                   float* bf, int* __restrict__ bh, int* flag,
                                                   int n, int L_, int E, int nchunk) {
    int blk = blockIdx.x;
    if (blk < nchunk) {
        __shared__ int h[256];
        h[threadIdx.x] = 0;
        __syncthreads();
        int cs = blk * CHUNK;
        int ce = min(cs + CHUNK, E);
        for (int i = cs + threadIdx.x; i < ce; i += 256)
            atomicAdd(&h[dst[i] >> BSHIFT], 1);
        __syncthreads();
        bh[threadIdx.x * nchunk + blk] = h[threadIdx.x];
        return;
    }
    int isbf = detect_bf16_blk((const unsigned int*)emb);
    int i = (blk - nchunk) * 256 + threadIdx.x;
    if (blk == nchunk && threadIdx.x == 0) *flag = isbf;
    if (i < n) x0[i] = f2h_u(load_in(emb, i, isbf));
    if (i < L_ * 4096) {
        int l = i >> 12, rem = i & 4095;
        int k = rem >> 6, c64 = rem & 63;
        int t = c64 >> 4, c = c64 & 15;
        int kf = k >> 5, quad = (k >> 3) & 3, j = k & 7;
        int f = t * 2 + kf, lane = quad * 16 + c;
        Whf[l * FRAG_STRIDE + (f * 64 + lane) * 8 + j] = f2h_u(load_in(W, i, isbf));
    }
    if (i < L_ * 1024) {                 // score tile: frags 8 (k<32), 9 (k>=32)
        int l = i >> 10, r = i & 1023;
        int kf = r >> 9, rr = r & 511;
        int lane = rr >> 3, j = rr & 7;
        int c = lane & 15, quad = lane >> 4;
        int k = kf * 32 + quad * 8 + j;
        float val = 0.f;
        if (c < 2) {
            const void* av = c ? ad_ : as_;
            float dot = 0.f;
            for (int cc = 0; cc < 64; ++cc)
                dot += load_in(W, l * 4096 + k * 64 + cc, isbf) * load_in(av, l * 64 + cc, isbf);
            val = dot;                   // (W @ a)[k]
        }
        Whf[l * FRAG_STRIDE + ((8 + kf) * 64 + lane) * 8 + j] = f2h_u(val);
    }
    if (i < L_ * 64) bf[i] = load_in(b_, i, isbf);
}

// ---- CSR build -------------------------------------------------------------

// block per bucket: exclusive scan of the chunk row (nchunk <= 512), total->ghist
__global__ __launch_bounds__(256) void scanb_k(int* __restrict__ bh, int* __restrict__ ghist,
                                               int nchunk) {
    __shared__ int s[256];
    int b = blockIdx.x, t = threadIdx.x;
    int i0 = 2 * t, i1 = 2 * t + 1;
    int v0 = (i0 < nchunk) ? bh[b * nchunk + i0] : 0;
    int v1 = (i1 < nchunk) ? bh[b * nchunk + i1] : 0;
    int p = v0 + v1;
    s[t] = p;
    __syncthreads();
    for (int off = 1; off < 256; off <<= 1) {
        int tv = (t >= off) ? s[t - off] : 0;
        __syncthreads();
        s[t] += tv;
        __syncthreads();
    }
    int excl = s[t] - p;
    if (i0 < nchunk) bh[b * nchunk + i0] = excl;
    if (i1 < nchunk) bh[b * nchunk + i1] = excl + v0;
    if (t == 255) ghist[b] = s[255];
}

// single block: cross-bucket exclusive scans (pairs sizes, col sizes)
__global__ __launch_bounds__(256) void scan_nb_k(const int* ghist, int* pairs_base, int* col_base,
                                                 int* rowptr, int N, int E, int NB) {
    __shared__ int s1[256], s2[256];
    int t = threadIdx.x;
    int hv = (t < NB) ? ghist[t] : 0;
    int npb = (t < NB) ? min(N - (t << BSHIFT), NPB) : 0;
    s1[t] = hv; s2[t] = hv + npb;
    __syncthreads();
    for (int off = 1; off < 256; off <<= 1) {
        int t1 = (t >= off) ? s1[t - off] : 0;
        int t2 = (t >= off) ? s2[t - off] : 0;
        __syncthreads();
        s1[t] += t1; s2[t] += t2;
        __syncthreads();
    }
    if (t < NB) {
        pairs_base[t] = s1[t] - hv;
        col_base[t]   = s2[t] - (hv + npb);
    }
    if (t == 0) rowptr[N] = E + N;
}

// one pass, zero global atomics: base from scanned histograms, rank via LDS.
// pair packed: src (23b) | local-dst (9b) << 23
__global__ __launch_bounds__(256) void partition_k(const int* __restrict__ src,
                                                   const int* __restrict__ dst,
                                                   const int* __restrict__ bh,
                                                   const int* __restrict__ pairs_base,
                                                   unsigned int* __restrict__ pairs,
                                                   int E, int NB, int nchunk) {
    __shared__ int base[256], rk[256];
    int t = threadIdx.x;
    base[t] = (t < NB) ? pairs_base[t] + bh[t * nchunk + blockIdx.x] : 0;
    rk[t] = 0;
    __syncthreads();
    int cs = blockIdx.x * CHUNK;
    int ce = min(cs + CHUNK, E);
    for (int i = cs + t; i < ce; i += 256) {
        int d = dst[i];
        int b = d >> BSHIFT;
        int r = atomicAdd(&rk[b], 1);
        pairs[base[b] + r] = (unsigned)src[i] | ((unsigned)(d & (NPB - 1)) << 23);
    }
}

__global__ __launch_bounds__(512) void build_k(const unsigned int* __restrict__ pairs,
                                               const int* __restrict__ ghist,
                                               const int* __restrict__ pairs_base,
                                               const int* __restrict__ col_base,
                                               int* __restrict__ rowptr, int* __restrict__ col,
                                               int N) {
    __shared__ int cnt[512], cnt2[512], sc[512], off[513];
    __shared__ int col_lds[COL_CAP];
    int b = blockIdx.x, t = threadIdx.x;
    int nloc = min(N - (b << BSHIFT), NPB);
    int ne = ghist[b], pb = pairs_base[b], cb = col_base[b];
    cnt[t] = 0; cnt2[t] = 0;
    __syncthreads();
    for (int i = t; i < ne; i += 512)
        atomicAdd(&cnt[pairs[pb + i] >> 23], 1);
    __syncthreads();
    int v = cnt[t] + (t < nloc ? 1 : 0);    // +1 self loop
    sc[t] = v;
    __syncthreads();
    for (int o = 1; o < 512; o <<= 1) {
        int tv = (t >= o) ? sc[t - o] : 0;
        __syncthreads();
        sc[t] += tv;
        __syncthreads();
    }
    off[t + 1] = sc[t];
    if (t == 0) off[0] = 0;
    __syncthreads();
    if (t < nloc) rowptr[(b << BSHIFT) + t] = cb + off[t];
    int total = off[nloc];                   // == ne + nloc
    bool fit = (total <= COL_CAP);
    for (int i = t; i < ne; i += 512) {
        unsigned int p = pairs[pb + i];
        int loc = p >> 23;
        int pos = off[loc] + atomicAdd(&cnt2[loc], 1);
        int sv = (int)(p & 0x7FFFFFu);
        if (fit) col_lds[pos] = sv;
        else     col[cb + pos] = sv;         // overflow fallback
    }
    if (t < nloc) {
        int pos = off[t + 1] - 1;            // self-loop slot
        int sv = (b << BSHIFT) + t;
        if (fit) col_lds[pos] = sv;
        else     col[cb + pos] = sv;
    }
    __syncthreads();
    if (fit)
        for (int i = t; i < total; i += 512) col[cb + i] = col_lds[i];
}

// ---- per-layer compute -----------------------------------------------------

// MFMA GEMM, 16-node strip per wave, 5 col-tiles (4 = h, 1 = scores).
// A: row=lane&15, k=(lane>>4)*8+j.  C: col=lane&15, row=(lane>>4)*4+reg.
__global__ __launch_bounds__(256) void gemm_k(const unsigned short* __restrict__ x,
                                              const unsigned short* __restrict__ Whf,
                                              unsigned short* __restrict__ h,
                                              float* __restrict__ es, float* __restrict__ ed,
                                              int n, int nblk, int nwaves) {
    int lane = threadIdx.x & 63;
    int gwave = (blockIdx.x * 256 + threadIdx.x) >> 6;
    int c = lane & 15, quad = lane >> 4;

    v8h bfr[10];
    #pragma unroll
    for (int f = 0; f < 10; ++f)
        bfr[f] = *(const v8h*)(Whf + (size_t)(f * 64 + lane) * 8);

    v4f z = {0.f, 0.f, 0.f, 0.f};
    for (int nb = gwave; nb < nblk; nb += nwaves) {
        int base = nb * 16;
        int m = base + c; if (m >= n) m = n - 1;
        const v8h a0 = *(const v8h*)(x + (size_t)m * 64 + quad * 8);
        const v8h a1 = *(const v8h*)(x + (size_t)m * 64 + 32 + quad * 8);
        v4f acc[5];
        #pragma unroll
        for (int t = 0; t < 5; ++t) {
            acc[t] = __builtin_amdgcn_mfma_f32_16x16x32_f16(a0, bfr[2 * t], z, 0, 0, 0);
            acc[t] = __builtin_amdgcn_mfma_f32_16x16x32_f16(a1, bfr[2 * t + 1], acc[t], 0, 0, 0);
        }
        #pragma unroll
        for (int r = 0; r < 4; ++r) {
            int row = base + quad * 4 + r;
            if (row < n) {
                #pragma unroll
                for (int t = 0; t < 4; ++t)
                    h[(size_t)row * 64 + t * 16 + c] = f2h_u(acc[t][r]);
                if (c == 0) es[row] = acc[4][r];
                if (c == 1) ed[row] = acc[4][r];
            }
        }
    }
}

__device__ inline float elu_f(float v) { return v > 0.f ? v : (__expf(v) - 1.f); }

// Two dst nodes per wave (node0: lanes 0-31, node1: lanes 32-63).
// Fast path (both deg<=32): single-pass softmax WITHOUT max subtraction
// (mathematically identical alpha; |e| ~ O(1) so no overflow), edge cache in
// registers, 16 h-rows in flight per node. write_out: fuse 4-layer mean.
__global__ __launch_bounds__(256) void agg_k(const unsigned short* __restrict__ h,
                                             const float* __restrict__ es,
                                             const float* __restrict__ ed, const int* __restrict__ rowptr,
                                             const int* __restrict__ col, const float* __restrict__ bias,
                                             unsigned short* __restrict__ xo,
                                             const unsigned short* __restrict__ x0,
                                             const unsigned short* __restrict__ x1,
                                             const unsigned short* __restrict__ x2,
                                             void* __restrict__ out, const int* __restrict__ flag,
                                             int write_out, int n) {
    int wv = (blockIdx.x * 256 + threadIdx.x) >> 6;
    int lane = threadIdx.x & 63;
    int n0 = wv * 2;
    if (n0 >= n) return;
    int half = lane >> 5, hl = lane & 31;
    int node = n0 + half;
    bool valid = node < n;
    int nodeC = valid ? node : n - 1;
    int r0 = rowptr[nodeC];
    int deg = valid ? (rowptr[nodeC + 1] - r0) : 0;

    if (__ballot(deg > 32) == 0) {
        float edd = valid ? ed[nodeC] : 0.f;
        int c = 0;
        float ex = 0.f;
        if (hl < deg) {
            c = col[r0 + hl];
            float t = es[(unsigned)c] + edd;
            t = t > 0.f ? t : 0.2f * t;
            ex = __expf(t);                    // no max-sub: |t| small, exact same alpha
        }
        float sum = ex;
        #pragma unroll
        for (int off = 1; off < 32; off <<= 1) sum += __shfl_xor(sum, off);
        float a = ex / (sum + 1e-16f);

        int deg0 = __shfl(deg, 0), deg1 = __shfl(deg, 32);
        int g = lane >> 3, j = lane & 7;       // 8 edge groups x 8 lanes x 16B
        unsigned joff = (unsigned)j * 8;
        float acc0[8], acc1[8];
        #pragma unroll
        for (int i = 0; i < 8; ++i) { acc0[i] = 0.f; acc1[i] = 0.f; }

        for (int t = 0; t < deg0; t += 16) {
            int i0 = t + g, i1 = t + 8 + g;
            int   s0  = __shfl(c, i0), s1 = __shfl(c, i1);
            float al0 = __shfl(a, i0), al1 = __shfl(a, i1);
            bool p0 = i0 < deg0, p1 = i1 < deg0;
            u16x8 hv0, hv1;
            if (p0) hv0 = *(const u16x8*)(h + ((unsigned)s0 * 64u + joff));
            if (p1) hv1 = *(const u16x8*)(h + ((unsigned)s1 * 64u + joff));
            if (p0) {
                #pragma unroll
                for (int i = 0; i < 8; ++i) acc0[i] = fmaf(al0, h2f_u(hv0[i]), acc0[i]);
            }
            if (p1) {
                #pragma unroll
                for (int i = 0; i < 8; ++i) acc0[i] = fmaf(al1, h2f_u(hv1[i]), acc0[i]);
            }
        }
        for (int t = 0; t < deg1; t += 16) {
            int i0 = t + g, i1 = t + 8 + g;
            int   s0  = __shfl(c, 32 + i0), s1 = __shfl(c, 32 + i1);
            float al0 = __shfl(a, 32 + i0), al1 = __shfl(a, 32 + i1);
            bool p0 = i0 < deg1, p1 = i1 < deg1;
            u16x8 hv0, hv1;
            if (p0) hv0 = *(const u16x8*)(h + ((unsigned)s0 * 64u + joff));
            if (p1) hv1 = *(const u16x8*)(h + ((unsigned)s1 * 64u + joff));
            if (p0) {
                #pragma unroll
                for (int i = 0; i < 8; ++i) acc1[i] = fmaf(al0, h2f_u(hv0[i]), acc1[i]);
            }
            if (p1) {
                #pragma unroll
                for (int i = 0; i < 8; ++i) acc1[i] = fmaf(al1, h2f_u(hv1[i]), acc1[i]);
            }
        }
        #pragma unroll
        for (int off = 8; off < 64; off <<= 1)
            #pragma unroll
            for (int i = 0; i < 8; ++i) {
                acc0[i] += __shfl_xor(acc0[i], off);
                acc1[i] += __shfl_xor(acc1[i], off);
            }

        // lanes 0-7 write node0, lanes 8-15 write node1
        if (g < 2) {
            int wnode = n0 + g;
            if (wnode < n) {
                size_t base = (size_t)wnode * 64 + joff;
                float y[8];
                #pragma unroll
                for (int i = 0; i < 8; ++i) {
                    float v = g ? acc1[i] : acc0[i];
                    y[i] = elu_f(v + bias[j * 8 + i]);
                }
                if (write_out) {
                    u16x8 a0v = *(const u16x8*)(x0 + base);
                    u16x8 a1v = *(const u16x8*)(x1 + base);
                    u16x8 a2v = *(const u16x8*)(x2 + base);
                    float v[8];
                    #pragma unroll
                    for (int i = 0; i < 8; ++i)
                        v[i] = (h2f_u(a0v[i]) + h2f_u(a1v[i]) + h2f_u(a2v[i]) + y[i]) * 0.25f;
                    if (*flag) {
                        u16x8 o;
                        #pragma unroll
                        for (int i = 0; i < 8; ++i) o[i] = f2bf(v[i]);
                        *(u16x8*)((unsigned short*)out + base) = o;
                    } else {
                        float4 o0 = make_float4(v[0], v[1], v[2], v[3]);
                        float4 o1 = make_float4(v[4], v[5], v[6], v[7]);
                        *(float4*)((float*)out + base) = o0;
                        *(float4*)((float*)out + base + 4) = o1;
                    }
                } else {
                    u16x8 o;
                    #pragma unroll
                    for (int i = 0; i < 8; ++i) o[i] = f2h_u(y[i]);
                    *(u16x8*)(xo + base) = o;
                }
            }
        }
    } else {
        // rare slow path: both nodes sequentially, 64-lane 3-pass scalar
        for (int k = 0; k < 2; ++k) {
            int nk = n0 + k;
            if (nk >= n) break;
            int start = __shfl(r0, k * 32);
            int end = start + __shfl(deg, k * 32);
            float edd = ed[nk];
            float m = -1e30f;
            for (int kk = start + lane; kk < end; kk += 64) {
                float e = es[col[kk]] + edd;
                e = e > 0.f ? e : 0.2f * e;
                m = fmaxf(m, e);
            }
            #pragma unroll
            for (int off = 32; off; off >>= 1) m = fmaxf(m, __shfl_xor(m, off));
            float sum = 0.f;
            for (int kk = start + lane; kk < end; kk += 64) {
                float e = es[col[kk]] + edd;
                e = e > 0.f ? e : 0.2f * e;
                sum += __expf(e - m);
            }
            #pragma unroll
            for (int off = 32; off; off >>= 1) sum += __shfl_xor(sum, off);
            float inv = 1.f / (sum + 1e-16f);
            float acc = 0.f;
            for (int kk = start; kk < end; ++kk) {
                int s = col[kk];
                float e = es[s] + edd;
                e = e > 0.f ? e : 0.2f * e;
                float al = __expf(e - m) * inv;
                acc = fmaf(al, h2f_u(h[(size_t)s * 64 + lane]), acc);
            }
            size_t base = (size_t)nk * 64 + lane;
            float y = elu_f(acc + bias[lane]);
            if (write_out) {
                float v = (h2f_u(x0[base]) + h2f_u(x1[base]) + h2f_u(x2[base]) + y) * 0.25f;
                if (*flag) ((unsigned short*)out)[base] = f2bf(v);
                else       ((float*)out)[base] = v;
            } else {
                xo[base] = f2h_u(y);
            }
        }
    }
}

// ---------------------------------------------------------------------------

extern "C" void kernel_launch(void* const* d_in, const int* in_sizes, int n_in,
                              void* d_out, int out_size, void* d_ws, size_t ws_size,
                              hipStream_t stream) {
    const int*  edge = (const int*)d_in[0];
    const void* emb  = d_in[1];
    const void* W    = d_in[2];
    const void* as_  = d_in[3];
    const void* ad_  = d_in[4];
    const void* b_   = d_in[5];

    const int E = in_sizes[0] / 2;
    const int N = in_sizes[1] / 64;
    const int L = in_sizes[2] / 4096;
    const int NB = (N + NPB - 1) >> BSHIFT;     // 196 buckets (<=256)
    const int nchunk = (E + CHUNK - 1) / CHUNK; // 196 (<=512)
    const size_t N64 = (size_t)N * 64;

    char* p = (char*)d_ws;
    auto take = [&](size_t bytes) { char* r = p; p += (bytes + 255) & ~(size_t)255; return r; };
    unsigned short* x0 = (unsigned short*)take(N64 * 2);
    unsigned short* x1 = (unsigned short*)take(N64 * 2);
    unsigned short* x3 = (unsigned short*)take(N64 * 2);
    unsigned short* h  = (unsigned short*)take(N64 * 2);
    unsigned int* pairs = (unsigned int*)take((size_t)E * 4 > N64 * 2 ? (size_t)E * 4 : N64 * 2);
    unsigned short* x2 = (unsigned short*)pairs;   // pairs dead after build_k
    float* es      = (float*)take((size_t)N * 4);
    float* ed      = (float*)take((size_t)N * 4);
    unsigned short* Whf = (unsigned short*)take((size_t)L * FRAG_STRIDE * 2);
    float* bf      = (float*)take((size_t)L * 64 * 4);
    int* rowptr    = (int*)take((size_t)(N + 1) * 4);
    int* col       = (int*)take((size_t)(E + N) * 4);
    int* bh        = (int*)take((size_t)256 * 512 * 4);
    int* ghist     = (int*)take(256 * 4);
    int* pairs_base= (int*)take(256 * 4);
    int* col_base  = (int*)take(256 * 4);
    int* flag      = (int*)take(4);

    const int* srcp = edge;
    const int* dstp = edge + E;
    const int convblocks = (int)((N64 + 255) / 256);

    conv_hist_k<<<nchunk + convblocks, 256, 0, stream>>>(emb, W, as_, ad_, b_, dstp, x0, Whf, bf,
                                                         bh, flag, (int)N64, L, E, nchunk);
    scanb_k<<<NB, 256, 0, stream>>>(bh, ghist, nchunk);
    scan_nb_k<<<1, 256, 0, stream>>>(ghist, pairs_base, col_base, rowptr, N, E, NB);
    partition_k<<<nchunk, 256, 0, stream>>>(srcp, dstp, bh, pairs_base, pairs, E, NB, nchunk);
    build_k<<<NB, 512, 0, stream>>>(pairs, ghist, pairs_base, col_base, rowptr, col, N);

    const int nblk = (N + 15) / 16;
    const int ggrid = 512;                      // 2048 waves, ~3 strips each
    // 2 nodes/wave, 4 waves/block -> 8 nodes/block (R6 bug: half this count)
    const int aggblocks = (N + 7) / 8;
    unsigned short* xs[4] = {x0, x1, x2, x3};
    for (int l = 0; l < L; ++l) {
        gemm_k<<<ggrid, 256, 0, stream>>>(xs[l], Whf + (size_t)l * FRAG_STRIDE,
                                          h, es, ed, N, nblk, ggrid * 4);
        agg_k<<<aggblocks, 256, 0, stream>>>(h, es, ed, rowptr, col, bf + l * 64,
                                             xs[l + 1], x0, x1, x2, d_out, flag,
                                             (l == L - 1) ? 1 : 0, N);
    }
}

// Round 10
// 334.267 us; speedup vs baseline: 1.1225x; 1.0350x over previous
//
#include <hip/hip_runtime.h>
#include <hip/hip_bf16.h>

// ---------------------------------------------------------------------------
// GAT forward: 3 layers, N=100k nodes, D=64, E=1.6M edges (+N self loops).
// CSR build atomic-free at global scope, pairs packed to u32 (src|local<<23):
//   conv_hist_k -> scanb_k -> scan_nb_k -> partition_k -> build_k
// Per layer: gemm_k (MFMA f16, pre-swizzled B frags, scores via augmented
// 5th col-tile), agg_k (2 dst nodes/wave, no-max softmax, PREFETCHED
// straight-line gather: h-row loads issue before the softmax reduce so their
// latency overlaps it). Last agg fuses the 4-layer mean.
// R9: fix R8 compile error (#pragma on same line as code) via fma8 helper.
// ---------------------------------------------------------------------------

#define BSHIFT 9
#define NPB 512            // nodes per bucket
#define COL_CAP 10240      // LDS col image capacity per bucket (mean ~8700)
#define FRAG_STRIDE 5120   // 10 frags * 64 lanes * 8 halves per layer
#define CHUNK 8192         // edges per partition chunk

typedef _Float16 v8h __attribute__((ext_vector_type(8)));
typedef float v4f __attribute__((ext_vector_type(4)));
typedef unsigned short u16x8 __attribute__((ext_vector_type(8)));

__device__ inline float bf2f(unsigned short u) {
    return __uint_as_float(((unsigned int)u) << 16);
}
__device__ inline unsigned short f2bf(float v) {
    __hip_bfloat16 b = __float2bfloat16(v);
    return *reinterpret_cast<unsigned short*>(&b);
}
__device__ inline unsigned short f2h_u(float v) {
    return __builtin_bit_cast(unsigned short, (_Float16)v);
}
__device__ inline float h2f_u(unsigned short u) {
    return (float)__builtin_bit_cast(_Float16, u);
}

__device__ __forceinline__ void fma8(float* acc, float al, const u16x8& hv) {
    #pragma unroll
    for (int i = 0; i < 8; ++i) acc[i] = fmaf(al, h2f_u(hv[i]), acc[i]);
}

__device__ inline float load_in(const void* p, int i, int isbf) {
    if (isbf) return bf2f(((const unsigned short*)p)[i]);
    return ((const float*)p)[i];
}

// per-block dtype detection: all blocks sample the same first 1KB of emb ->
// deterministic identical answer (bf16 ~97% exponent-byte hits, f32 ~4%).
__device__ inline int detect_bf16_blk(const unsigned int* raw) {
    __shared__ int s4[4];
    unsigned int b = (raw[threadIdx.x] >> 8) & 0x7Fu;
    unsigned long long m = __ballot(b >= 0x3Bu && b <= 0x3Fu);
    int wv = threadIdx.x >> 6;
    if ((threadIdx.x & 63) == 0) s4[wv] = __popcll(m);
    __syncthreads();
    return (s4[0] + s4[1] + s4[2] + s4[3]) > 128 ? 1 : 0;
}

// blocks [0, nchunk): per-chunk bucket histogram (no global atomics)
// blocks [nchunk, ...): conversions (emb->x0 fp16, W->frags, bias), flag store
__global__ __launch_bounds__(256) void conv_hist_k(const void* emb, const void* W, const void* as_,
                                                   const void* ad_, const void* b_,
                                                   const int* __restrict__ dst,
                                                   unsigned short* x0, unsigned short* Whf,
                                                   float* bf, int* __restrict__ bh, int* flag,
                                                   int n, int L_, int E, int nchunk) {
    int blk = blockIdx.x;
    if (blk < nchunk) {
        __shared__ int h[256];
        h[threadIdx.x] = 0;
        __syncthreads();
        int cs = blk * CHUNK;
        int ce = min(cs + CHUNK, E);
        for (int i = cs + threadIdx.x; i < ce; i += 256)
            atomicAdd(&h[dst[i] >> BSHIFT], 1);
        __syncthreads();
        bh[threadIdx.x * nchunk + blk] = h[threadIdx.x];
        return;
    }
    int isbf = detect_bf16_blk((const unsigned int*)emb);
    int i = (blk - nchunk) * 256 + threadIdx.x;
    if (blk == nchunk && threadIdx.x == 0) *flag = isbf;
    if (i < n) x0[i] = f2h_u(load_in(emb, i, isbf));
    if (i < L_ * 4096) {
        int l = i >> 12, rem = i & 4095;
        int k = rem >> 6, c64 = rem & 63;
        int t = c64 >> 4, c = c64 & 15;
        int kf = k >> 5, quad = (k >> 3) & 3, j = k & 7;
        int f = t * 2 + kf, lane = quad * 16 + c;
        Whf[l * FRAG_STRIDE + (f * 64 + lane) * 8 + j] = f2h_u(load_in(W, i, isbf));
    }
    if (i < L_ * 1024) {                 // score tile: frags 8 (k<32), 9 (k>=32)
        int l = i >> 10, r = i & 1023;
        int kf = r >> 9, rr = r & 511;
        int lane = rr >> 3, j = rr & 7;
        int c = lane & 15, quad = lane >> 4;
        int k = kf * 32 + quad * 8 + j;
        float val = 0.f;
        if (c < 2) {
            const void* av = c ? ad_ : as_;
            float dot = 0.f;
            for (int cc = 0; cc < 64; ++cc)
                dot += load_in(W, l * 4096 + k * 64 + cc, isbf) * load_in(av, l * 64 + cc, isbf);
            val = dot;                   // (W @ a)[k]
        }
        Whf[l * FRAG_STRIDE + ((8 + kf) * 64 + lane) * 8 + j] = f2h_u(val);
    }
    if (i < L_ * 64) bf[i] = load_in(b_, i, isbf);
}

// ---- CSR build -------------------------------------------------------------

// block per bucket: exclusive scan of the chunk row (nchunk <= 512), total->ghist
__global__ __launch_bounds__(256) void scanb_k(int* __restrict__ bh, int* __restrict__ ghist,
                                               int nchunk) {
    __shared__ int s[256];
    int b = blockIdx.x, t = threadIdx.x;
    int i0 = 2 * t, i1 = 2 * t + 1;
    int v0 = (i0 < nchunk) ? bh[b * nchunk + i0] : 0;
    int v1 = (i1 < nchunk) ? bh[b * nchunk + i1] : 0;
    int p = v0 + v1;
    s[t] = p;
    __syncthreads();
    for (int off = 1; off < 256; off <<= 1) {
        int tv = (t >= off) ? s[t - off] : 0;
        __syncthreads();
        s[t] += tv;
        __syncthreads();
    }
    int excl = s[t] - p;
    if (i0 < nchunk) bh[b * nchunk + i0] = excl;
    if (i1 < nchunk) bh[b * nchunk + i1] = excl + v0;
    if (t == 255) ghist[b] = s[255];
}

// single block: cross-bucket exclusive scans (pairs sizes, col sizes)
__global__ __launch_bounds__(256) void scan_nb_k(const int* ghist, int* pairs_base, int* col_base,
                                                 int* rowptr, int N, int E, int NB) {
    __shared__ int s1[256], s2[256];
    int t = threadIdx.x;
    int hv = (t < NB) ? ghist[t] : 0;
    int npb = (t < NB) ? min(N - (t << BSHIFT), NPB) : 0;
    s1[t] = hv; s2[t] = hv + npb;
    __syncthreads();
    for (int off = 1; off < 256; off <<= 1) {
        int t1 = (t >= off) ? s1[t - off] : 0;
        int t2 = (t >= off) ? s2[t - off] : 0;
        __syncthreads();
        s1[t] += t1; s2[t] += t2;
        __syncthreads();
    }
    if (t < NB) {
        pairs_base[t] = s1[t] - hv;
        col_base[t]   = s2[t] - (hv + npb);
    }
    if (t == 0) rowptr[N] = E + N;
}

// one pass, zero global atomics: base from scanned histograms, rank via LDS.
// pair packed: src (23b) | local-dst (9b) << 23
__global__ __launch_bounds__(256) void partition_k(const int* __restrict__ src,
                                                   const int* __restrict__ dst,
                                                   const int* __restrict__ bh,
                                                   const int* __restrict__ pairs_base,
                                                   unsigned int* __restrict__ pairs,
                                                   int E, int NB, int nchunk) {
    __shared__ int base[256], rk[256];
    int t = threadIdx.x;
    base[t] = (t < NB) ? pairs_base[t] + bh[t * nchunk + blockIdx.x] : 0;
    rk[t] = 0;
    __syncthreads();
    int cs = blockIdx.x * CHUNK;
    int ce = min(cs + CHUNK, E);
    for (int i = cs + t; i < ce; i += 256) {
        int d = dst[i];
        int b = d >> BSHIFT;
        int r = atomicAdd(&rk[b], 1);
        pairs[base[b] + r] = (unsigned)src[i] | ((unsigned)(d & (NPB - 1)) << 23);
    }
}

__global__ __launch_bounds__(512) void build_k(const unsigned int* __restrict__ pairs,
                                               const int* __restrict__ ghist,
                                               const int* __restrict__ pairs_base,
                                               const int* __restrict__ col_base,
                                               int* __restrict__ rowptr, int* __restrict__ col,
                                               int N) {
    __shared__ int cnt[512], cnt2[512], sc[512], off[513];
    __shared__ int col_lds[COL_CAP];
    int b = blockIdx.x, t = threadIdx.x;
    int nloc = min(N - (b << BSHIFT), NPB);
    int ne = ghist[b], pb = pairs_base[b], cb = col_base[b];
    cnt[t] = 0; cnt2[t] = 0;
    __syncthreads();
    for (int i = t; i < ne; i += 512)
        atomicAdd(&cnt[pairs[pb + i] >> 23], 1);
    __syncthreads();
    int v = cnt[t] + (t < nloc ? 1 : 0);    // +1 self loop
    sc[t] = v;
    __syncthreads();
    for (int o = 1; o < 512; o <<= 1) {
        int tv = (t >= o) ? sc[t - o] : 0;
        __syncthreads();
        sc[t] += tv;
        __syncthreads();
    }
    off[t + 1] = sc[t];
    if (t == 0) off[0] = 0;
    __syncthreads();
    if (t < nloc) rowptr[(b << BSHIFT) + t] = cb + off[t];
    int total = off[nloc];                   // == ne + nloc
    bool fit = (total <= COL_CAP);
    for (int i = t; i < ne; i += 512) {
        unsigned int p = pairs[pb + i];
        int loc = p >> 23;
        int pos = off[loc] + atomicAdd(&cnt2[loc], 1);
        int sv = (int)(p & 0x7FFFFFu);
        if (fit) col_lds[pos] = sv;
        else     col[cb + pos] = sv;         // overflow fallback
    }
    if (t < nloc) {
        int pos = off[t + 1] - 1;            // self-loop slot
        int sv = (b << BSHIFT) + t;
        if (fit) col_lds[pos] = sv;
        else     col[cb + pos] = sv;
    }
    __syncthreads();
    if (fit)
        for (int i = t; i < total; i += 512) col[cb + i] = col_lds[i];
}

// ---- per-layer compute -----------------------------------------------------

// MFMA GEMM, 16-node strip per wave, 5 col-tiles (4 = h, 1 = scores).
// A: row=lane&15, k=(lane>>4)*8+j.  C: col=lane&15, row=(lane>>4)*4+reg.
__global__ __launch_bounds__(256) void gemm_k(const unsigned short* __restrict__ x,
                                              const unsigned short* __restrict__ Whf,
                                              unsigned short* __restrict__ h,
                                              float* __restrict__ es, float* __restrict__ ed,
                                              int n, int nblk, int nwaves) {
    int lane = threadIdx.x & 63;
    int gwave = (blockIdx.x * 256 + threadIdx.x) >> 6;
    int c = lane & 15, quad = lane >> 4;

    v8h bfr[10];
    #pragma unroll
    for (int f = 0; f < 10; ++f)
        bfr[f] = *(const v8h*)(Whf + (size_t)(f * 64 + lane) * 8);

    v4f z = {0.f, 0.f, 0.f, 0.f};
    for (int nb = gwave; nb < nblk; nb += nwaves) {
        int base = nb * 16;
        int m = base + c; if (m >= n) m = n - 1;
        const v8h a0 = *(const v8h*)(x + (size_t)m * 64 + quad * 8);
        const v8h a1 = *(const v8h*)(x + (size_t)m * 64 + 32 + quad * 8);
        v4f acc[5];
        #pragma unroll
        for (int t = 0; t < 5; ++t) {
            acc[t] = __builtin_amdgcn_mfma_f32_16x16x32_f16(a0, bfr[2 * t], z, 0, 0, 0);
            acc[t] = __builtin_amdgcn_mfma_f32_16x16x32_f16(a1, bfr[2 * t + 1], acc[t], 0, 0, 0);
        }
        #pragma unroll
        for (int r = 0; r < 4; ++r) {
            int row = base + quad * 4 + r;
            if (row < n) {
                #pragma unroll
                for (int t = 0; t < 4; ++t)
                    h[(size_t)row * 64 + t * 16 + c] = f2h_u(acc[t][r]);
                if (c == 0) es[row] = acc[4][r];
                if (c == 1) ed[row] = acc[4][r];
            }
        }
    }
}

__device__ inline float elu_f(float v) { return v > 0.f ? v : (__expf(v) - 1.f); }

// Two dst nodes per wave (node0: lanes 0-31, node1: lanes 32-63).
// Fast path (both deg<=32), fully straight-line:
//   1. col load -> es gather + iteration-0 h-loads issued IMMEDIATELY
//   2. softmax (exp + 5-shfl reduce) overlaps those load latencies
//   3. iteration-1 h-loads issue, then iter-0 fmas (overlap), then iter-1 fmas
// Per-lane accumulation order identical to R7 -> bit-identical numerics.
__global__ __launch_bounds__(256) void agg_k(const unsigned short* __restrict__ h,
                                             const float* __restrict__ es,
                                             const float* __restrict__ ed, const int* __restrict__ rowptr,
                                             const int* __restrict__ col, const float* __restrict__ bias,
                                             unsigned short* __restrict__ xo,
                                             const unsigned short* __restrict__ x0,
                                             const unsigned short* __restrict__ x1,
                                             const unsigned short* __restrict__ x2,
                                             void* __restrict__ out, const int* __restrict__ flag,
                                             int write_out, int n) {
    int wv = (blockIdx.x * 256 + threadIdx.x) >> 6;
    int lane = threadIdx.x & 63;
    int n0 = wv * 2;
    if (n0 >= n) return;
    int half = lane >> 5, hl = lane & 31;
    int node = n0 + half;
    bool valid = node < n;
    int nodeC = valid ? node : n - 1;
    int r0 = rowptr[nodeC];
    int deg = valid ? (rowptr[nodeC + 1] - r0) : 0;

    if (__ballot(deg > 32) == 0) {
        float edd = valid ? ed[nodeC] : 0.f;
        bool has = hl < deg;
        int c = 0;
        float esv = 0.f;
        if (has) {
            c = col[r0 + hl];
            esv = es[(unsigned)c];              // issue scattered es load early
        }

        int deg0 = __shfl(deg, 0), deg1 = __shfl(deg, 32);
        int g = lane >> 3, j = lane & 7;        // 8 edge groups x 8 lanes x 16B
        unsigned joff = (unsigned)j * 8;
        int i0 = g, i1 = 8 + g;

        // ---- iteration-0 prefetch: 16 rows across both nodes, issued
        // before the softmax reduce so load latency overlaps it ----
        int s00 = __shfl(c, i0), s01 = __shfl(c, i1);
        int s10 = __shfl(c, 32 + i0), s11 = __shfl(c, 32 + i1);
        bool p00 = i0 < deg0, p01 = i1 < deg0;
        bool p10 = i0 < deg1, p11 = i1 < deg1;
        u16x8 h00, h01, h10, h11;
        if (p00) h00 = *(const u16x8*)(h + ((unsigned)s00 * 64u + joff));
        if (p01) h01 = *(const u16x8*)(h + ((unsigned)s01 * 64u + joff));
        if (p10) h10 = *(const u16x8*)(h + ((unsigned)s10 * 64u + joff));
        if (p11) h11 = *(const u16x8*)(h + ((unsigned)s11 * 64u + joff));

        // ---- softmax (no max-sub; |e| small) ----
        float ex = 0.f;
        if (has) {
            float t = esv + edd;
            t = t > 0.f ? t : 0.2f * t;
            ex = __expf(t);
        }
        float sum = ex;
        #pragma unroll
        for (int off = 1; off < 32; off <<= 1) sum += __shfl_xor(sum, off);
        float a = ex / (sum + 1e-16f);

        float a00 = __shfl(a, i0), a01 = __shfl(a, i1);
        float a10 = __shfl(a, 32 + i0), a11 = __shfl(a, 32 + i1);

        // ---- iteration-1 loads (deg>16 lanes only) issue before iter-0 fmas ----
        int i2 = 16 + g, i3 = 24 + g;
        int s02 = __shfl(c, i2), s03 = __shfl(c, i3);
        int s12 = __shfl(c, 32 + i2), s13 = __shfl(c, 32 + i3);
        bool p02 = i2 < deg0, p03 = i3 < deg0;
        bool p12 = i2 < deg1, p13 = i3 < deg1;
        u16x8 h02, h03, h12, h13;
        if (p02) h02 = *(const u16x8*)(h + ((unsigned)s02 * 64u + joff));
        if (p03) h03 = *(const u16x8*)(h + ((unsigned)s03 * 64u + joff));
        if (p12) h12 = *(const u16x8*)(h + ((unsigned)s12 * 64u + joff));
        if (p13) h13 = *(const u16x8*)(h + ((unsigned)s13 * 64u + joff));
        float a02 = __shfl(a, i2), a03 = __shfl(a, i3);
        float a12 = __shfl(a, 32 + i2), a13 = __shfl(a, 32 + i3);

        float acc0[8], acc1[8];
        #pragma unroll
        for (int i = 0; i < 8; ++i) { acc0[i] = 0.f; acc1[i] = 0.f; }
        // iter-0 fmas (same per-lane order as R7: i0, i1)
        if (p00) fma8(acc0, a00, h00);
        if (p01) fma8(acc0, a01, h01);
        if (p10) fma8(acc1, a10, h10);
        if (p11) fma8(acc1, a11, h11);
        // iter-1 fmas (i2, i3)
        if (p02) fma8(acc0, a02, h02);
        if (p03) fma8(acc0, a03, h03);
        if (p12) fma8(acc1, a12, h12);
        if (p13) fma8(acc1, a13, h13);

        #pragma unroll
        for (int off = 8; off < 64; off <<= 1)
            #pragma unroll
            for (int i = 0; i < 8; ++i) {
                acc0[i] += __shfl_xor(acc0[i], off);
                acc1[i] += __shfl_xor(acc1[i], off);
            }

        // lanes 0-7 write node0, lanes 8-15 write node1
        if (g < 2) {
            int wnode = n0 + g;
            if (wnode < n) {
                size_t base = (size_t)wnode * 64 + joff;
                float y[8];
                #pragma unroll
                for (int i = 0; i < 8; ++i) {
                    float v = g ? acc1[i] : acc0[i];
                    y[i] = elu_f(v + bias[j * 8 + i]);
                }
                if (write_out) {
                    u16x8 a0v = *(const u16x8*)(x0 + base);
                    u16x8 a1v = *(const u16x8*)(x1 + base);
                    u16x8 a2v = *(const u16x8*)(x2 + base);
                    float v[8];
                    #pragma unroll
                    for (int i = 0; i < 8; ++i)
                        v[i] = (h2f_u(a0v[i]) + h2f_u(a1v[i]) + h2f_u(a2v[i]) + y[i]) * 0.25f;
                    if (*flag) {
                        u16x8 o;
                        #pragma unroll
                        for (int i = 0; i < 8; ++i) o[i] = f2bf(v[i]);
                        *(u16x8*)((unsigned short*)out + base) = o;
                    } else {
                        float4 o0 = make_float4(v[0], v[1], v[2], v[3]);
                        float4 o1 = make_float4(v[4], v[5], v[6], v[7]);
                        *(float4*)((float*)out + base) = o0;
                        *(float4*)((float*)out + base + 4) = o1;
                    }
                } else {
                    u16x8 o;
                    #pragma unroll
                    for (int i = 0; i < 8; ++i) o[i] = f2h_u(y[i]);
                    *(u16x8*)(xo + base) = o;
                }
            }
        }
    } else {
        // rare slow path: both nodes sequentially, 64-lane 3-pass scalar
        for (int k = 0; k < 2; ++k) {
            int nk = n0 + k;
            if (nk >= n) break;
            int start = __shfl(r0, k * 32);
            int end = start + __shfl(deg, k * 32);
            float edd = ed[nk];
            float m = -1e30f;
            for (int kk = start + lane; kk < end; kk += 64) {
                float e = es[col[kk]] + edd;
                e = e > 0.f ? e : 0.2f * e;
                m = fmaxf(m, e);
            }
            #pragma unroll
            for (int off = 32; off; off >>= 1) m = fmaxf(m, __shfl_xor(m, off));
            float sum = 0.f;
            for (int kk = start + lane; kk < end; kk += 64) {
                float e = es[col[kk]] + edd;
                e = e > 0.f ? e : 0.2f * e;
                sum += __expf(e - m);
            }
            #pragma unroll
            for (int off = 32; off; off >>= 1) sum += __shfl_xor(sum, off);
            float inv = 1.f / (sum + 1e-16f);
            float acc = 0.f;
            for (int kk = start; kk < end; ++kk) {
                int s = col[kk];
                float e = es[s] + edd;
                e = e > 0.f ? e : 0.2f * e;
                float al = __expf(e - m) * inv;
                acc = fmaf(al, h2f_u(h[(size_t)s * 64 + lane]), acc);
            }
            size_t base = (size_t)nk * 64 + lane;
            float y = elu_f(acc + bias[lane]);
            if (write_out) {
                float v = (h2f_u(x0[base]) + h2f_u(x1[base]) + h2f_u(x2[base]) + y) * 0.25f;
                if (*flag) ((unsigned short*)out)[base] = f2bf(v);
                else       ((float*)out)[base] = v;
            } else {
                xo[base] = f2h_u(y);
            }
        }
    }
}

// ---------------------------------------------------------------------------

extern "C" void kernel_launch(void* const* d_in, const int* in_sizes, int n_in,
                              void* d_out, int out_size, void* d_ws, size_t ws_size,
                              hipStream_t stream) {
    const int*  edge = (const int*)d_in[0];
    const void* emb  = d_in[1];
    const void* W    = d_in[2];
    const void* as_  = d_in[3];
    const void* ad_  = d_in[4];
    const void* b_   = d_in[5];

    const int E = in_sizes[0] / 2;
    const int N = in_sizes[1] / 64;
    const int L = in_sizes[2] / 4096;
    const int NB = (N + NPB - 1) >> BSHIFT;     // 196 buckets (<=256)
    const int nchunk = (E + CHUNK - 1) / CHUNK; // 196 (<=512)
    const size_t N64 = (size_t)N * 64;

    char* p = (char*)d_ws;
    auto take = [&](size_t bytes) { char* r = p; p += (bytes + 255) & ~(size_t)255; return r; };
    unsigned short* x0 = (unsigned short*)take(N64 * 2);
    unsigned short* x1 = (unsigned short*)take(N64 * 2);
    unsigned short* x3 = (unsigned short*)take(N64 * 2);
    unsigned short* h  = (unsigned short*)take(N64 * 2);
    unsigned int* pairs = (unsigned int*)take((size_t)E * 4 > N64 * 2 ? (size_t)E * 4 : N64 * 2);
    unsigned short* x2 = (unsigned short*)pairs;   // pairs dead after build_k
    float* es      = (float*)take((size_t)N * 4);
    float* ed      = (float*)take((size_t)N * 4);
    unsigned short* Whf = (unsigned short*)take((size_t)L * FRAG_STRIDE * 2);
    float* bf      = (float*)take((size_t)L * 64 * 4);
    int* rowptr    = (int*)take((size_t)(N + 1) * 4);
    int* col       = (int*)take((size_t)(E + N) * 4);
    int* bh        = (int*)take((size_t)256 * 512 * 4);
    int* ghist     = (int*)take(256 * 4);
    int* pairs_base= (int*)take(256 * 4);
    int* col_base  = (int*)take(256 * 4);
    int* flag      = (int*)take(4);

    const int* srcp = edge;
    const int* dstp = edge + E;
    const int convblocks = (int)((N64 + 255) / 256);

    conv_hist_k<<<nchunk + convblocks, 256, 0, stream>>>(emb, W, as_, ad_, b_, dstp, x0, Whf, bf,
                                                         bh, flag, (int)N64, L, E, nchunk);
    scanb_k<<<NB, 256, 0, stream>>>(bh, ghist, nchunk);
    scan_nb_k<<<1, 256, 0, stream>>>(ghist, pairs_base, col_base, rowptr, N, E, NB);
    partition_k<<<nchunk, 256, 0, stream>>>(srcp, dstp, bh, pairs_base, pairs, E, NB, nchunk);
    build_k<<<NB, 512, 0, stream>>>(pairs, ghist, pairs_base, col_base, rowptr, col, N);

    const int nblk = (N + 15) / 16;
    const int ggrid = 512;                      // 2048 waves, ~3 strips each
    const int aggblocks = (N + 7) / 8;          // 2 nodes/wave, 4 waves/block
    unsigned short* xs[4] = {x0, x1, x2, x3};
    for (int l = 0; l < L; ++l) {
        gemm_k<<<ggrid, 256, 0, stream>>>(xs[l], Whf + (size_t)l * FRAG_STRIDE,
                                          h, es, ed, N, nblk, ggrid * 4);
        agg_k<<<aggblocks, 256, 0, stream>>>(h, es, ed, rowptr, col, bf + l * 64,
                                             xs[l + 1], x0, x1, x2, d_out, flag,
                                             (l == L - 1) ? 1 : 0, N);
    }
}